// Round 3
// baseline (396.721 us; speedup 1.0000x reference)
//
#include <hip/hip_runtime.h>

// Embedding gather: out[r, :] = table[idx[r], :]
// rows = BATCH*NUM_FEATS = 819200, D = 64 floats (256 B) per row.
// 16 lanes per row, float4 per lane -> 16 B/lane, 256 B per row segment.
//
// v4 (= v3 with compile fix: __builtin_nontemporal_store needs a NATIVE
// clang vector type, not HIP's float4 class):
//  - non-temporal stores for `out` (210 MB write-once stream): preserve
//    L2/L3 capacity for the 256 MB table (fits Infinity Cache; ~32% of
//    gathers are re-touches that can hit if table lines survive).
//  - 4-row unroll per thread: 4 independent gather loads in flight before
//    any store -> 4x outstanding miss-lines per wave vs baseline
//    (attacks MSHR/latency limit).

#define LANES_PER_ROW 16  // EMBED_DIM * 4 bytes / 16 bytes per lane

typedef float floatx4 __attribute__((ext_vector_type(4)));  // native vec

__global__ __launch_bounds__(256) void hh_embed_gather(
    const int* __restrict__ idx,
    const floatx4* __restrict__ table,  // table as 16B vecs: V x 16
    floatx4* __restrict__ out,          // out as 16B vecs:  rows x 16
    int n_rows, int quarter_rows)
{
    int tid  = blockIdx.x * blockDim.x + threadIdx.x;
    int row0 = tid >> 4;        // / LANES_PER_ROW
    int lane = tid & 15;        // % LANES_PER_ROW
    if (row0 >= quarter_rows) return;
    int row1 = row0 + quarter_rows;
    int row2 = row1 + quarter_rows;
    int row3 = row2 + quarter_rows;
    bool has1 = (row1 < n_rows);
    bool has2 = (row2 < n_rows);
    bool has3 = (row3 < n_rows);

    // idx: tiny (3.3 MB), broadcast within each 16-lane group (same line).
    int t0 = idx[row0];
    int t1 = has1 ? idx[row1] : 0;
    int t2 = has2 ? idx[row2] : 0;
    int t3 = has3 ? idx[row3] : 0;

    // Four INDEPENDENT gathers issued back-to-back (cached path: the table
    // is the reuse carrier and should stay L3-resident).
    floatx4 v0 = table[(long long)t0 * LANES_PER_ROW + lane];
    floatx4 v1 = table[(long long)t1 * LANES_PER_ROW + lane];
    floatx4 v2 = table[(long long)t2 * LANES_PER_ROW + lane];
    floatx4 v3 = table[(long long)t3 * LANES_PER_ROW + lane];

    // out: write-once stream -> non-temporal, don't pollute L2/L3.
    __builtin_nontemporal_store(v0, out + (long long)row0 * LANES_PER_ROW + lane);
    if (has1) __builtin_nontemporal_store(v1, out + (long long)row1 * LANES_PER_ROW + lane);
    if (has2) __builtin_nontemporal_store(v2, out + (long long)row2 * LANES_PER_ROW + lane);
    if (has3) __builtin_nontemporal_store(v3, out + (long long)row3 * LANES_PER_ROW + lane);
}

extern "C" void kernel_launch(void* const* d_in, const int* in_sizes, int n_in,
                              void* d_out, int out_size, void* d_ws, size_t ws_size,
                              hipStream_t stream) {
    const int*   idx   = (const int*)d_in[0];     // [B*F] int32
    const float* table = (const float*)d_in[1];   // [V, 64] fp32
    float*       out   = (float*)d_out;           // [B*F, 64] fp32

    int n_rows = in_sizes[0];                     // 819200
    int quarter_rows = (n_rows + 3) / 4;
    long long total_threads = (long long)quarter_rows * LANES_PER_ROW;
    int block = 256;
    int grid  = (int)((total_threads + block - 1) / block);

    hh_embed_gather<<<grid, block, 0, stream>>>(
        idx, (const floatx4*)table, (floatx4*)out, n_rows, quarter_rows);
}